// Round 4
// baseline (152.226 us; speedup 1.0000x reference)
//
#include <hip/hip_runtime.h>
#include <stdint.h>

#define NE 8
#define ND 512
#define NH1 512
#define NH2 256
#define NY 256
#define NB 8192
#define BM 128
#define BK 32
#define MAXT (NB/BM + NE - 1)   /* 71 */
#define PADROWS (NB + BM)       /* 8320 */

typedef float f32x4 __attribute__((ext_vector_type(4)));
typedef __bf16 bf16x8 __attribute__((ext_vector_type(8)));
typedef unsigned short u16x8 __attribute__((ext_vector_type(8)));

__device__ __forceinline__ unsigned short f2bf(float f) {
  unsigned int u = __float_as_uint(f);
  u += 0x7fffu + ((u >> 16) & 1u);   // round-to-nearest-even
  return (unsigned short)(u >> 16);
}

__device__ __forceinline__ void async_cp16(const void* g, void* l) {
  __builtin_amdgcn_global_load_lds((const __attribute__((address_space(1))) void*)g,
                                   (__attribute__((address_space(3))) void*)l,
                                   16, 0, 0);
}

__device__ __forceinline__ int clampe(int g) {
  return g < 0 ? 0 : (g > NE - 1 ? NE - 1 : g);
}

// meta (ints): [0..7] counts, [8..15] offs, [24] ntiles, [32..127] tile table,
//              [128..383] blockhist[b][e], [512..767] base[b][e]

__global__ void hist_rank_k(const int* __restrict__ gate, int* __restrict__ meta,
                            int* __restrict__ rank) {
  __shared__ int lc[NE];
  int tid = threadIdx.x;
  if (tid < NE) lc[tid] = 0;
  __syncthreads();
  int row = blockIdx.x * 256 + tid;
  int g = clampe(gate[row]);
  rank[row] = atomicAdd(&lc[g], 1);
  __syncthreads();
  if (tid < NE) meta[128 + blockIdx.x * NE + tid] = lc[tid];
}

__global__ void scan_k(int* __restrict__ meta) {
  __shared__ int hist[256];
  __shared__ int basel[256];
  __shared__ int cnt[NE];
  int tid = threadIdx.x;
  hist[tid] = meta[128 + tid];            // [b][e] layout: b*8+e
  __syncthreads();
  if (tid < NE) {
    int run = 0;
    for (int b = 0; b < 32; b++) {
      basel[b * NE + tid] = run;
      run += hist[b * NE + tid];
    }
    cnt[tid] = run;
  }
  __syncthreads();
  __shared__ int offs[NE];
  if (tid == 0) {
    int off = 0, t = 0;
    for (int e = 0; e < NE; e++) {
      int c = cnt[e];
      meta[e] = c;
      meta[8 + e] = off;
      offs[e] = off;
      int ntl = (c + BM - 1) / BM;
      for (int i = 0; i < ntl; i++) meta[32 + t++] = (e << 16) | i;
      off += c;
    }
    meta[24] = t;
  }
  __syncthreads();
  meta[512 + tid] = offs[tid & (NE - 1)] + basel[tid];
}

// perm_k: wave-free tiny kernel building perm[slot] = row  (256 thr x 32 blocks)
__global__ void perm_k(const int* __restrict__ gate, const int* __restrict__ rank,
                       const int* __restrict__ meta, int* __restrict__ perm) {
  int row = blockIdx.x * 256 + threadIdx.x;
  int g = clampe(gate[row]);
  int slot = meta[512 + (row >> 8) * NE + g] + rank[row];
  perm[slot] = row;
}

// All three W [G][K][N] fp32 -> Wt [G][N][K] bf16 in ONE launch (LDS-tiled transpose)
#define W1T (NE * (ND/32) * (NH1/32))   /* 2048 */
#define W2T (NE * (NH1/32) * (NH2/32))  /* 1024 */
#define W3T (NE * (NH2/32) * (NY/32))   /* 512  */
__global__ void wtrans_all_k(const float* __restrict__ W1, const float* __restrict__ W2,
                             const float* __restrict__ W3,
                             unsigned short* __restrict__ w1t, unsigned short* __restrict__ w2t,
                             unsigned short* __restrict__ w3t) {
  __shared__ float t[32][33];
  int b = blockIdx.x;
  const float* src; unsigned short* dst; int K, N, idx;
  if (b < W1T)            { src = W1; dst = w1t; K = ND;  N = NH1; idx = b; }
  else if (b < W1T + W2T) { src = W2; dst = w2t; K = NH1; N = NH2; idx = b - W1T; }
  else                    { src = W3; dst = w3t; K = NH2; N = NY;  idx = b - W1T - W2T; }
  int ntn = N >> 5, ntk = K >> 5;
  int n0 = (idx % ntn) * 32;
  int k0 = ((idx / ntn) % ntk) * 32;
  int g  = idx / (ntn * ntk);
  int tx = threadIdx.x, ty = threadIdx.y;
  src += (size_t)g * K * N;
  #pragma unroll
  for (int r = 0; r < 32; r += 8)
    t[ty + r][tx] = src[(size_t)(k0 + ty + r) * N + n0 + tx];
  __syncthreads();
  dst += (size_t)g * N * K;
  #pragma unroll
  for (int r = 0; r < 32; r += 8)
    dst[(size_t)(n0 + ty + r) * K + k0 + tx] = f2bf(t[tx][ty + r]);
}

// GEMM1 with fused row-gather: A comes straight from h[perm[...]] (fp32 -> bf16
// in registers -> ds_write). As layout is k-quad-major: As[q][r][8] so both the
// staging writes and the MFMA fragment reads are 16B-contiguous, 2-way bank
// aliased (free per m136). B via global_load_lds width=16. BM=128, BN=128.
__global__ __launch_bounds__(256)
void gemm1_k(const float* __restrict__ h,
             const unsigned short* __restrict__ Bt,
             const float* __restrict__ bias,
             const int* __restrict__ meta,
             const int* __restrict__ perm,
             unsigned short* __restrict__ Obf)
{
  constexpr int K = ND, N = NH1, BN = 128;
  __shared__ unsigned short As[BM * BK];  // [q][r][8]
  __shared__ unsigned short Bs[BN * BK];  // [n][k]

  if ((int)blockIdx.y >= meta[24]) return;
  int ent  = meta[32 + blockIdx.y];
  int e    = ent >> 16;
  int trow = ent & 0xffff;
  int cnt  = meta[e];
  int off  = meta[8 + e];
  int row0 = trow * BM;

  const unsigned short* Be = Bt + ((size_t)e * N + (size_t)blockIdx.x * BN) * K;

  int tid  = threadIdx.x;
  int wave = tid >> 6, lane = tid & 63;
  int wx = wave & 1, wy = wave >> 1;
  int lm = lane & 15, quad = lane >> 4;
  int srow = lane >> 2;
  int scol = (lane & 3) * 8;

  // gather assignment: thread -> (row r, col half c0)
  int r  = tid >> 1;            // 0..127
  int c0 = (tid & 1) * 16;      // 0 or 16
  int grow_g = row0 + r;
  int prow = (grow_g < cnt) ? perm[off + grow_g] : 0;
  const float* hrow = h + (size_t)prow * K;

  f32x4 acc[4][4];
  f32x4 zero = {0.f, 0.f, 0.f, 0.f};
  #pragma unroll
  for (int mi = 0; mi < 4; mi++)
    #pragma unroll
    for (int ni = 0; ni < 4; ni++)
      acc[mi][ni] = zero;

  for (int k0 = 0; k0 < K; k0 += BK) {
    // B: 8 chunks over 4 waves
    #pragma unroll
    for (int i = 0; i < 2; i++) {
      int c = wave + i * 4;
      async_cp16(Be + (size_t)(c * 16 + srow) * K + k0 + scol, &Bs[c * 512]);
    }
    // A: gather 16 fp32, convert, stage
    float4 f0 = *(const float4*)(hrow + k0 + c0);
    float4 f1 = *(const float4*)(hrow + k0 + c0 + 4);
    float4 f2 = *(const float4*)(hrow + k0 + c0 + 8);
    float4 f3 = *(const float4*)(hrow + k0 + c0 + 12);
    union { u16x8 v; unsigned short u[8]; } p0, p1;
    p0.u[0] = f2bf(f0.x); p0.u[1] = f2bf(f0.y); p0.u[2] = f2bf(f0.z); p0.u[3] = f2bf(f0.w);
    p0.u[4] = f2bf(f1.x); p0.u[5] = f2bf(f1.y); p0.u[6] = f2bf(f1.z); p0.u[7] = f2bf(f1.w);
    p1.u[0] = f2bf(f2.x); p1.u[1] = f2bf(f2.y); p1.u[2] = f2bf(f2.z); p1.u[3] = f2bf(f2.w);
    p1.u[4] = f2bf(f3.x); p1.u[5] = f2bf(f3.y); p1.u[6] = f2bf(f3.z); p1.u[7] = f2bf(f3.w);
    int q0 = c0 >> 3;
    *(u16x8*)&As[((q0 + 0) * 128 + r) * 8] = p0.v;
    *(u16x8*)&As[((q0 + 1) * 128 + r) * 8] = p1.v;
    __syncthreads();
    bf16x8 af[4], bfr[4];
    #pragma unroll
    for (int mi = 0; mi < 4; mi++)
      af[mi] = *reinterpret_cast<const bf16x8*>(&As[(quad * 128 + wy * 64 + mi * 16 + lm) * 8]);
    #pragma unroll
    for (int ni = 0; ni < 4; ni++)
      bfr[ni] = *reinterpret_cast<const bf16x8*>(&Bs[(wx * 64 + ni * 16 + lm) * BK + quad * 8]);
    #pragma unroll
    for (int mi = 0; mi < 4; mi++)
      #pragma unroll
      for (int ni = 0; ni < 4; ni++)
        acc[mi][ni] = __builtin_amdgcn_mfma_f32_16x16x32_bf16(af[mi], bfr[ni], acc[mi][ni], 0, 0, 0);
    __syncthreads();
  }

  #pragma unroll
  for (int mi = 0; mi < 4; mi++) {
    #pragma unroll
    for (int ni = 0; ni < 4; ni++) {
      int col = blockIdx.x * BN + wx * 64 + ni * 16 + lm;
      float bv = bias[e * N + col];
      #pragma unroll
      for (int rr = 0; rr < 4; rr++) {
        int ml   = wy * 64 + mi * 16 + quad * 4 + rr;
        int grow = row0 + ml;
        if (grow < cnt) {
          float v = acc[mi][ni][rr] + bv;
          v = (v > 0.f) ? v : 0.2f * v;
          Obf[(size_t)(off + grow) * N + col] = f2bf(v);
        }
      }
    }
  }
}

// Layers 2/3: sorted bf16 A, BN=64 for 2x the blocks (284 = 1.1/CU).
// 4 waves 2x2, wave tile 64x32: 8 MFMA : 6 ds_read_b128 per k-iter.
template<int BN, int K, int N, bool LEAKY, bool SCATTER>
__global__ __launch_bounds__(256)
void gemm_k(const unsigned short* __restrict__ A,
            const unsigned short* __restrict__ Bt,
            const float* __restrict__ bias,
            const int* __restrict__ meta,
            const int* __restrict__ perm,
            unsigned short* __restrict__ Obf,
            float* __restrict__ Ofp)
{
  constexpr int WN = BN / 2;
  constexpr int FN = WN / 16;
  constexpr int CA = BM * BK * 2 / 1024;
  constexpr int CB = BN * BK * 2 / 1024;
  constexpr int CT = CA + CB;

  __shared__ unsigned short As[BM * BK];
  __shared__ unsigned short Bs[BN * BK];

  if ((int)blockIdx.y >= meta[24]) return;
  int ent  = meta[32 + blockIdx.y];
  int e    = ent >> 16;
  int trow = ent & 0xffff;
  int cnt  = meta[e];
  int off  = meta[8 + e];
  int row0 = trow * BM;

  const unsigned short* Ae = A + (size_t)(off + row0) * K;
  const unsigned short* Be = Bt + ((size_t)e * N + (size_t)blockIdx.x * BN) * K;

  int tid  = threadIdx.x;
  int wave = tid >> 6, lane = tid & 63;
  int wx = wave & 1, wy = wave >> 1;
  int lm = lane & 15, quad = lane >> 4;
  int srow = lane >> 2;
  int scol = (lane & 3) * 8;

  f32x4 acc[4][FN];
  f32x4 zero = {0.f, 0.f, 0.f, 0.f};
  #pragma unroll
  for (int mi = 0; mi < 4; mi++)
    #pragma unroll
    for (int ni = 0; ni < FN; ni++)
      acc[mi][ni] = zero;

  for (int k0 = 0; k0 < K; k0 += BK) {
    for (int c = wave; c < CT; c += 4) {
      if (c < CA)
        async_cp16(Ae + (size_t)(c * 16 + srow) * K + k0 + scol, &As[c * 512]);
      else
        async_cp16(Be + (size_t)((c - CA) * 16 + srow) * K + k0 + scol, &Bs[(c - CA) * 512]);
    }
    __syncthreads();
    bf16x8 af[4], bfr[FN];
    #pragma unroll
    for (int mi = 0; mi < 4; mi++)
      af[mi] = *reinterpret_cast<const bf16x8*>(&As[(wy * 64 + mi * 16 + lm) * BK + quad * 8]);
    #pragma unroll
    for (int ni = 0; ni < FN; ni++)
      bfr[ni] = *reinterpret_cast<const bf16x8*>(&Bs[(wx * WN + ni * 16 + lm) * BK + quad * 8]);
    #pragma unroll
    for (int mi = 0; mi < 4; mi++)
      #pragma unroll
      for (int ni = 0; ni < FN; ni++)
        acc[mi][ni] = __builtin_amdgcn_mfma_f32_16x16x32_bf16(af[mi], bfr[ni], acc[mi][ni], 0, 0, 0);
    __syncthreads();
  }

  #pragma unroll
  for (int mi = 0; mi < 4; mi++) {
    #pragma unroll
    for (int ni = 0; ni < FN; ni++) {
      int col = blockIdx.x * BN + wx * WN + ni * 16 + lm;
      float bv = bias[e * N + col];
      #pragma unroll
      for (int r = 0; r < 4; r++) {
        int ml   = wy * 64 + mi * 16 + quad * 4 + r;
        int grow = row0 + ml;
        if (grow < cnt) {
          float v = acc[mi][ni][r] + bv;
          if (LEAKY) v = (v > 0.f) ? v : 0.2f * v;
          int s = off + grow;
          if (SCATTER)
            Ofp[(size_t)perm[s] * N + col] = v;
          else
            Obf[(size_t)s * N + col] = f2bf(v);
        }
      }
    }
  }
}

extern "C" void kernel_launch(void* const* d_in, const int* in_sizes, int n_in,
                              void* d_out, int out_size, void* d_ws, size_t ws_size,
                              hipStream_t stream) {
  (void)in_sizes; (void)n_in; (void)out_size; (void)ws_size;
  const float* h  = (const float*)d_in[0];
  const int* gate = (const int*)d_in[1];
  const float* W1 = (const float*)d_in[2];
  const float* b1 = (const float*)d_in[3];
  const float* W2 = (const float*)d_in[4];
  const float* b2 = (const float*)d_in[5];
  const float* W3 = (const float*)d_in[6];
  const float* b3 = (const float*)d_in[7];
  float* out = (float*)d_out;

  char* ws = (char*)d_ws;
  int* meta = (int*)ws;                               // 4096 B
  int* rank = (int*)(ws + 4096);                      // 32 KB
  int* perm = (int*)(ws + 4096 + 32768);              // 32 KB
  unsigned short* a1s = (unsigned short*)(ws + 4096 + 65536);
  unsigned short* a2s = a1s + (size_t)PADROWS * NH1;
  unsigned short* w1t = a2s + (size_t)PADROWS * NH2;
  unsigned short* w2t = w1t + (size_t)NE * ND * NH1;
  unsigned short* w3t = w2t + (size_t)NE * NH1 * NH2;

  hist_rank_k<<<NB / 256, 256, 0, stream>>>(gate, meta, rank);
  scan_k<<<1, 256, 0, stream>>>(meta);
  perm_k<<<NB / 256, 256, 0, stream>>>(gate, rank, meta, perm);
  wtrans_all_k<<<W1T + W2T + W3T, dim3(32, 8), 0, stream>>>(W1, W2, W3, w1t, w2t, w3t);

  gemm1_k<<<dim3(NH1 / 128, MAXT), 256, 0, stream>>>(h, w1t, b1, meta, perm, a1s);
  gemm_k<64, NH1, NH2, true, false><<<dim3(NH2 / 64, MAXT), 256, 0, stream>>>(
      a1s, w2t, b2, meta, perm, a2s, (float*)nullptr);
  gemm_k<64, NH2, NY, false, true><<<dim3(NY / 64, MAXT), 256, 0, stream>>>(
      a2s, w3t, b3, meta, perm, (unsigned short*)nullptr, out);
}

// Round 6
// 146.033 us; speedup vs baseline: 1.0424x; 1.0424x over previous
//
#include <hip/hip_runtime.h>
#include <stdint.h>

#define NE 8
#define ND 512
#define NH1 512
#define NH2 256
#define NY 256
#define NB 8192
#define BM2 64                   /* fused-tile rows */
#define BK 32
#define MAXT2 (NB/BM2 + NE - 1)  /* 135 */
#define W1T (NE * (ND/32) * (NH1/32))   /* 2048 */
#define W2T (NE * (NH1/32) * (NH2/32))  /* 1024 */
#define W3T (NE * (NH2/32) * (NY/32))   /* 512  */
#define WTT (W1T + W2T + W3T)           /* 3584 */

typedef float f32x4 __attribute__((ext_vector_type(4)));
typedef __bf16 bf16x8 __attribute__((ext_vector_type(8)));
typedef unsigned short u16x8 __attribute__((ext_vector_type(8)));

__device__ __forceinline__ unsigned short f2bf(float f) {
  unsigned int u = __float_as_uint(f);
  u += 0x7fffu + ((u >> 16) & 1u);   // round-to-nearest-even
  return (unsigned short)(u >> 16);
}

__device__ __forceinline__ void async_cp16(const void* g, void* l) {
  __builtin_amdgcn_global_load_lds((const __attribute__((address_space(1))) void*)g,
                                   (__attribute__((address_space(3))) void*)l,
                                   16, 0, 0);
}

__device__ __forceinline__ int clampe(int g) {
  return g < 0 ? 0 : (g > NE - 1 ? NE - 1 : g);
}

// meta ints: [0..7] counts, [8..15] offs, [24] ntiles, [1024..1163] tile table

// prep_k: blocks 0..WTT-1 transpose W (fp32 [g][k][n] -> bf16 [g][n][k]);
// block WTT runs a deterministic single-block counting sort (no global atomics).
__global__ __launch_bounds__(1024)
void prep_k(const int* __restrict__ gate,
            const float* __restrict__ W1, const float* __restrict__ W2,
            const float* __restrict__ W3,
            unsigned short* __restrict__ w1t, unsigned short* __restrict__ w2t,
            unsigned short* __restrict__ w3t,
            int* __restrict__ meta, int* __restrict__ perm)
{
  __shared__ char sm[36928] __attribute__((aligned(16)));
  int b = blockIdx.x, t = threadIdx.x;

  if (b < WTT) {
    float* tt = (float*)sm;   // [32][33]
    const float* src; unsigned short* dst; int K, N, idx;
    if (b < W1T)            { src = W1; dst = w1t; K = ND;  N = NH1; idx = b; }
    else if (b < W1T + W2T) { src = W2; dst = w2t; K = NH1; N = NH2; idx = b - W1T; }
    else                    { src = W3; dst = w3t; K = NH2; N = NY;  idx = b - W1T - W2T; }
    int ntn = N >> 5, ntk = K >> 5;
    int n0 = (idx % ntn) * 32;
    int k0 = ((idx / ntn) % ntk) * 32;
    int g  = idx / (ntn * ntk);
    int tx = t & 31, ty = t >> 5;       // 32 x 32, one element each
    const float* s = src + (size_t)g * K * N;
    tt[ty * 33 + tx] = s[(size_t)(k0 + ty) * N + n0 + tx];
    __syncthreads();
    unsigned short* d = dst + (size_t)g * N * K;
    d[(size_t)(n0 + ty) * K + k0 + tx] = f2bf(tt[tx * 33 + ty]);
    return;
  }

  // ---- sort block: 1024 threads x 8 rows each ----
  unsigned int* lcnt = (unsigned int*)sm;        // [1024]
  int* pre   = (int*)(sm + 4096);                // [NE][1024]
  int* cnt8  = (int*)(sm + 36864);               // [8]
  int* offs8 = cnt8 + 8;                         // [8]

  int g8[8];
  unsigned int c = 0;
  #pragma unroll
  for (int i = 0; i < 8; i++) {
    int g = clampe(gate[t * 8 + i]);
    g8[i] = g;
    c += 1u << (4 * g);
  }
  lcnt[t] = c;
  __syncthreads();

  int wave = t >> 6, lane = t & 63;
  if (wave < NE) {
    int e = wave;
    int carry = 0;
    for (int ch = 0; ch < 16; ch++) {
      int idx = ch * 64 + lane;
      int v = (int)((lcnt[idx] >> (4 * e)) & 15u);
      int s = v;
      #pragma unroll
      for (int d = 1; d < 64; d <<= 1) {
        int up = __shfl_up(s, d, 64);
        if (lane >= d) s += up;
      }
      pre[e * 1024 + idx] = carry + s - v;   // exclusive prefix
      carry += __shfl(s, 63, 64);
    }
    if (lane == 0) cnt8[e] = carry;
  }
  __syncthreads();

  if (t == 0) {
    int off = 0, tt2 = 0;
    for (int e = 0; e < NE; e++) {
      int cc = cnt8[e];
      meta[e] = cc;
      meta[8 + e] = off;
      offs8[e] = off;
      int ntl = (cc + BM2 - 1) / BM2;
      for (int i = 0; i < ntl; i++) meta[1024 + tt2++] = (e << 16) | i;
      off += cc;
    }
    meta[24] = tt2;
  }
  __syncthreads();

  unsigned int run = 0;
  #pragma unroll
  for (int i = 0; i < 8; i++) {
    int g = g8[i];
    int r = (int)((run >> (4 * g)) & 15u);
    run += 1u << (4 * g);
    perm[offs8[g] + pre[g * 1024 + t] + r] = t * 8 + i;
  }
}

// LDS map:
//   hstage: [0,4096)            64x32 bf16, quad-major [q][row][8]
//   Wst:    [4096,36864)        staged W chunk, [n][BK] bf16 (max 512x32)
//   a1:     [36864,103424)      64 x 520 bf16 (pad +8)
//   a2:     [103424,137216)     64 x 264 bf16 (pad +8)
#define SM_BYTES 137216

__global__ __launch_bounds__(256)
void mlp_k(const float* __restrict__ h,
           const float* __restrict__ b1, const float* __restrict__ b2,
           const float* __restrict__ b3,
           float* __restrict__ out,
           const int* __restrict__ meta, const int* __restrict__ perm,
           const unsigned short* __restrict__ w1t,
           const unsigned short* __restrict__ w2t,
           const unsigned short* __restrict__ w3t)
{
  __shared__ char smem[SM_BYTES] __attribute__((aligned(16)));
  __shared__ int permc[BM2];

  if ((int)blockIdx.x >= meta[24]) return;

  unsigned short* hstage = (unsigned short*)smem;
  unsigned short* Wst    = (unsigned short*)(smem + 4096);
  unsigned short* a1     = (unsigned short*)(smem + 36864);
  unsigned short* a2     = (unsigned short*)(smem + 103424);

  int tid  = threadIdx.x;
  int ent  = meta[1024 + blockIdx.x];
  int e    = ent >> 16;
  int trow = ent & 0xffff;
  int cnt  = meta[e];
  int off  = meta[8 + e];
  int row0 = trow * BM2;

  if (tid < BM2) {
    int grow = row0 + tid;
    permc[tid] = (grow < cnt) ? perm[off + grow] : 0;
  }
  __syncthreads();

  int wave = tid >> 6, lane = tid & 63;
  int lm = lane & 15, quad = lane >> 4;
  int srow = lane >> 2;          // staging row within 16-row/1KB unit
  int scol = (lane & 3) * 8;     // staging col (elements)
  int gr = tid >> 2;             // h-gather: row 0..63
  int gq = tid & 3;              // h-gather: k-quad
  const float* hrow = h + (size_t)permc[gr] * ND;

  f32x4 acc[4][8];
  f32x4 zero = {0.f, 0.f, 0.f, 0.f};

  // ---- Layer 1: a1[64][512] = leaky(h64 x W1 + b1) ----
  #pragma unroll
  for (int mi = 0; mi < 4; mi++)
    #pragma unroll
    for (int ni = 0; ni < 8; ni++)
      acc[mi][ni] = zero;

  const unsigned short* Be1 = w1t + (size_t)e * ND * NH1;
  for (int k0 = 0; k0 < ND; k0 += BK) {
    #pragma unroll
    for (int i = 0; i < 8; i++) {
      int u = wave + i * 4;
      async_cp16(Be1 + (size_t)(u * 16 + srow) * ND + k0 + scol, Wst + u * 512);
    }
    float4 f0 = *(const float4*)(hrow + k0 + gq * 8);
    float4 f1 = *(const float4*)(hrow + k0 + gq * 8 + 4);
    union { u16x8 v; unsigned short u[8]; } pk;
    pk.u[0] = f2bf(f0.x); pk.u[1] = f2bf(f0.y); pk.u[2] = f2bf(f0.z); pk.u[3] = f2bf(f0.w);
    pk.u[4] = f2bf(f1.x); pk.u[5] = f2bf(f1.y); pk.u[6] = f2bf(f1.z); pk.u[7] = f2bf(f1.w);
    *(u16x8*)(hstage + ((size_t)gq * 64 + gr) * 8) = pk.v;
    __syncthreads();
    bf16x8 af[4], bf[8];
    #pragma unroll
    for (int mi = 0; mi < 4; mi++)
      af[mi] = *reinterpret_cast<const bf16x8*>(hstage + (quad * 64 + mi * 16 + lm) * 8);
    #pragma unroll
    for (int ni = 0; ni < 8; ni++)
      bf[ni] = *reinterpret_cast<const bf16x8*>(Wst + (wave * 128 + ni * 16 + lm) * 32 + quad * 8);
    #pragma unroll
    for (int mi = 0; mi < 4; mi++)
      #pragma unroll
      for (int ni = 0; ni < 8; ni++)
        acc[mi][ni] = __builtin_amdgcn_mfma_f32_16x16x32_bf16(af[mi], bf[ni], acc[mi][ni], 0, 0, 0);
    __syncthreads();
  }
  #pragma unroll
  for (int mi = 0; mi < 4; mi++)
    #pragma unroll
    for (int ni = 0; ni < 8; ni++) {
      int col = wave * 128 + ni * 16 + lm;
      float bv = b1[e * NH1 + col];
      #pragma unroll
      for (int r = 0; r < 4; r++) {
        int row = mi * 16 + quad * 4 + r;
        float v = acc[mi][ni][r] + bv;
        v = (v > 0.f) ? v : 0.2f * v;
        a1[row * 520 + col] = f2bf(v);
      }
    }
  __syncthreads();

  // ---- Layer 2: a2[64][256] = leaky(a1 x W2 + b2) ----
  #pragma unroll
  for (int mi = 0; mi < 4; mi++)
    #pragma unroll
    for (int ni = 0; ni < 4; ni++)
      acc[mi][ni] = zero;

  const unsigned short* Be2 = w2t + (size_t)e * NH1 * NH2;
  for (int k0 = 0; k0 < NH1; k0 += BK) {
    #pragma unroll
    for (int i = 0; i < 4; i++) {
      int u = wave + i * 4;
      async_cp16(Be2 + (size_t)(u * 16 + srow) * NH1 + k0 + scol, Wst + u * 512);
    }
    __syncthreads();
    bf16x8 af[4], bf[4];
    #pragma unroll
    for (int mi = 0; mi < 4; mi++)
      af[mi] = *reinterpret_cast<const bf16x8*>(a1 + (mi * 16 + lm) * 520 + k0 + quad * 8);
    #pragma unroll
    for (int ni = 0; ni < 4; ni++)
      bf[ni] = *reinterpret_cast<const bf16x8*>(Wst + (wave * 64 + ni * 16 + lm) * 32 + quad * 8);
    #pragma unroll
    for (int mi = 0; mi < 4; mi++)
      #pragma unroll
      for (int ni = 0; ni < 4; ni++)
        acc[mi][ni] = __builtin_amdgcn_mfma_f32_16x16x32_bf16(af[mi], bf[ni], acc[mi][ni], 0, 0, 0);
    __syncthreads();
  }
  #pragma unroll
  for (int mi = 0; mi < 4; mi++)
    #pragma unroll
    for (int ni = 0; ni < 4; ni++) {
      int col = wave * 64 + ni * 16 + lm;
      float bv = b2[e * NH2 + col];
      #pragma unroll
      for (int r = 0; r < 4; r++) {
        int row = mi * 16 + quad * 4 + r;
        float v = acc[mi][ni][r] + bv;
        v = (v > 0.f) ? v : 0.2f * v;
        a2[row * 264 + col] = f2bf(v);
      }
    }
  __syncthreads();

  // ---- Layer 3: out[perm[row]][256] = a2 x W3 + b3 ----
  #pragma unroll
  for (int mi = 0; mi < 4; mi++)
    #pragma unroll
    for (int ni = 0; ni < 4; ni++)
      acc[mi][ni] = zero;

  const unsigned short* Be3 = w3t + (size_t)e * NH2 * NY;
  for (int k0 = 0; k0 < NH2; k0 += BK) {
    #pragma unroll
    for (int i = 0; i < 4; i++) {
      int u = wave + i * 4;
      async_cp16(Be3 + (size_t)(u * 16 + srow) * NH2 + k0 + scol, Wst + u * 512);
    }
    __syncthreads();
    bf16x8 af[4], bf[4];
    #pragma unroll
    for (int mi = 0; mi < 4; mi++)
      af[mi] = *reinterpret_cast<const bf16x8*>(a2 + (mi * 16 + lm) * 264 + k0 + quad * 8);
    #pragma unroll
    for (int ni = 0; ni < 4; ni++)
      bf[ni] = *reinterpret_cast<const bf16x8*>(Wst + (wave * 64 + ni * 16 + lm) * 32 + quad * 8);
    #pragma unroll
    for (int mi = 0; mi < 4; mi++)
      #pragma unroll
      for (int ni = 0; ni < 4; ni++)
        acc[mi][ni] = __builtin_amdgcn_mfma_f32_16x16x32_bf16(af[mi], bf[ni], acc[mi][ni], 0, 0, 0);
    __syncthreads();
  }
  #pragma unroll
  for (int mi = 0; mi < 4; mi++)
    #pragma unroll
    for (int ni = 0; ni < 4; ni++) {
      int col = wave * 64 + ni * 16 + lm;
      float bv = b3[e * NY + col];
      #pragma unroll
      for (int r = 0; r < 4; r++) {
        int row = mi * 16 + quad * 4 + r;
        int grow = row0 + row;
        if (grow < cnt) {
          float v = acc[mi][ni][r] + bv;
          out[(size_t)permc[row] * NY + col] = v;
        }
      }
    }
}

extern "C" void kernel_launch(void* const* d_in, const int* in_sizes, int n_in,
                              void* d_out, int out_size, void* d_ws, size_t ws_size,
                              hipStream_t stream) {
  (void)in_sizes; (void)n_in; (void)out_size; (void)ws_size;
  const float* h  = (const float*)d_in[0];
  const int* gate = (const int*)d_in[1];
  const float* W1 = (const float*)d_in[2];
  const float* b1 = (const float*)d_in[3];
  const float* W2 = (const float*)d_in[4];
  const float* b2 = (const float*)d_in[5];
  const float* W3 = (const float*)d_in[6];
  const float* b3 = (const float*)d_in[7];
  float* out = (float*)d_out;

  char* ws = (char*)d_ws;
  int* meta = (int*)ws;                               // 8 KB
  int* perm = (int*)(ws + 8192);                      // 32 KB
  unsigned short* w1t = (unsigned short*)(ws + 8192 + 32768);
  unsigned short* w2t = w1t + (size_t)NE * ND * NH1;
  unsigned short* w3t = w2t + (size_t)NE * NH1 * NH2;
  // ws total ~7.2 MB

  prep_k<<<WTT + 1, 1024, 0, stream>>>(gate, W1, W2, W3, w1t, w2t, w3t, meta, perm);
  mlp_k<<<MAXT2, 256, 0, stream>>>(h, b1, b2, b3, out, meta, perm, w1t, w2t, w3t);
}